// Round 6
// baseline (549.091 us; speedup 1.0000x reference)
//
#include <hip/hip_runtime.h>
#include <cstdint>
#include <cstddef>

#define TSEQ 2048
#define DDIM 1024

typedef _Float16 f16;
typedef _Float16 f16x2 __attribute__((ext_vector_type(2)));
typedef _Float16 f16x4 __attribute__((ext_vector_type(4)));
typedef _Float16 f16x8 __attribute__((ext_vector_type(8)));
typedef float f32x4 __attribute__((ext_vector_type(4)));

// q,k,v live in (b,h,t,d) layout. qwh/kwh are FRAG-MAJOR: frag f = n_tile*512+kc
// (n_tile = o>>4, kc = k>>5, k = w*1024+i); within frag, lane l = (o&15)+((k&31)>>3)*16
// holds 8 f16 (k&7). One frag = 1 KB = one MFMA B-operand in exact lane order.

__device__ __align__(16) static const unsigned char g_zero16[16] = {};

__device__ __forceinline__ void gload_lds16(const void* g, void* l) {
  __builtin_amdgcn_global_load_lds(
      (const __attribute__((address_space(1))) void*)g,
      (__attribute__((address_space(3))) void*)l, 16, 0, 0);
}

// ------------- fused fp32->fp16 converts (x, v_w, p_w) -------------
__global__ void cvt_all(const float* __restrict__ x, const float* __restrict__ vw,
                        const float* __restrict__ pw,
                        f16* __restrict__ xh, f16* __restrict__ vwh, f16* __restrict__ pwh) {
  int b = blockIdx.x;
  const float* src; f16* dst; int i;
  if (b < 4096)      { src = x;  dst = xh;  i = b * 256 + threadIdx.x; }
  else if (b < 5120) { src = vw; dst = vwh; i = (b - 4096) * 256 + threadIdx.x; }
  else               { src = pw; dst = pwh; i = (b - 5120) * 256 + threadIdx.x; }
  float4 v = ((const float4*)src)[i];
  f16x4 h = { (f16)v.x, (f16)v.y, (f16)v.z, (f16)v.w };
  ((f16x4*)dst)[i] = h;
}

// ------- conv weights w[o][i][W] -> frag-major f16 (see header comment) -------
// grid 2048 = {q,k} x o_tile(64) x i_block(16); LDS transpose, b128 both sides.
__global__ __launch_bounds__(256) void cvt_w_frag(const float* __restrict__ qw,
                                                  const float* __restrict__ kw,
                                                  f16* __restrict__ qd, f16* __restrict__ kd) {
  __shared__ __align__(16) f16 tile[16 * 1160];   // [o](stride 1160)[w](stride 72)[i:64]
  const int bid = blockIdx.x;
  const float* src = (bid < 1024) ? qw : kw;
  f16* dst = (bid < 1024) ? qd : kd;
  const int bb = bid & 1023;
  const int o_tile = bb >> 4;
  const int ib = bb & 15;
  const int i0 = ib * 64;
  const int tid = threadIdx.x;

  // phase 1: each (o,io,wq) slot reads 8 float4 (8 i's x 4 w's), writes 4x b128
  #pragma unroll
  for (int p = 0; p < 2; p++) {
    const int o_l = p * 8 + (tid >> 5);
    const int sub = tid & 31;
    const int io = sub >> 2;          // i-octet 0..7
    const int wq = sub & 3;           // w-quad 0..3
    const float* s = src + (size_t)(o_tile * 16 + o_l) * 16384 + (size_t)(i0 + io * 8) * 16 + wq * 4;
    float4 v[8];
    #pragma unroll
    for (int r = 0; r < 8; r++) v[r] = *(const float4*)(s + r * 16);
    f16* t = &tile[o_l * 1160 + io * 8];
    #pragma unroll
    for (int j = 0; j < 4; j++) {
      f16x8 hv;
      #pragma unroll
      for (int r = 0; r < 8; r++) hv[r] = (f16)((&v[r].x)[j]);
      *(f16x8*)&t[(wq * 4 + j) * 72] = hv;
    }
  }
  __syncthreads();
  // phase 2: emit 2048 16B chunks, coalesced frag-major writes
  #pragma unroll
  for (int p = 0; p < 8; p++) {
    const int c = p * 256 + tid;
    const int w = c >> 7;
    const int ksub = (c >> 6) & 1;
    const int l = c & 63;
    const int o_l = l & 15;
    const int i_local = ksub * 32 + ((l >> 4) << 3);
    f16x8 v = *(const f16x8*)&tile[o_l * 1160 + w * 72 + i_local];
    const int kc = w * 32 + ib * 2 + ksub;
    *(f16x8*)(dst + ((size_t)(o_tile * 512 + kc)) * 512 + l * 8) = v;
  }
}

// ------------- fused q+k conv-GEMM: A via LDS, B direct from global -------------
// Block tile m=128, n=64 (both q,k). 4 waves: wm=wid&1 (m-half), ks=wid>>1 (k-half
// of BK=64). B frags register-double-buffered one iter ahead (coalesced 1KB loads
// from frag-major layout). LDS holds only A (2 x 16KB), k-split reduced at end.
__global__ __launch_bounds__(256, 2) void gemm_qk(
    const f16* __restrict__ xh,
    const f16* __restrict__ Bq, const f16* __restrict__ Bk,
    const float* __restrict__ bq, const float* __restrict__ bk,
    f16* __restrict__ oq, f16* __restrict__ ok)
{
  __shared__ __align__(16) f16 smem[16384];   // 2 x A tile (128 rows x 64 f16)
  const int tid = threadIdx.x;
  const int lane = tid & 63;
  const int wid = tid >> 6;
  const int wm = wid & 1;
  const int ks = wid >> 1;

  const int m0 = blockIdx.x * 128;
  const int n0 = blockIdx.y * 64;
  const int bT = m0 & ~(TSEQ - 1);
  const int t0 = m0 & (TSEQ - 1);

  const int srow = lane >> 3;                           // staging row within inst
  const int scg = ((lane & 7) ^ ((lane >> 3) & 7)) * 8; // swizzled chunk (f16 units)

  f32x4 accq[4][4] = {};
  f32x4 acck[4][4] = {};

  // A read slot: chunk cg = ks*4+(lane>>4), slot = cg ^ (r&7), r&7 == lane&7
  const int slotoff = (((ks * 4 + (lane >> 4)) ^ (lane & 7)) * 8);
  // B frag base: frag (n0>>4 + j, (kk>>5)+ks), lane*8
  const size_t bbase = (size_t)(n0 >> 4) * 512 * 512 + (size_t)lane * 8;

  auto stageA = [&](int kk, int buf) {
    f16* sb = &smem[buf * 8192];
    const int w = kk >> 10;
    const int i0 = (kk & (DDIM - 1)) + scg;
    #pragma unroll
    for (int c = 0; c < 4; c++) {
      const int s = wid * 4 + c;
      const int r = s * 8 + srow;
      const int srcT = t0 + r + w - 15;
      const void* g = (srcT >= 0)
          ? (const void*)(xh + (((size_t)(bT + srcT)) << 10) + i0)
          : (const void*)g_zero16;
      gload_lds16(g, (void*)&sb[s * 512]);
    }
  };
  auto loadB = [&](int kk, f16x8* q, f16x8* k) {
    const int kc = (kk >> 5) + ks;
    #pragma unroll
    for (int j = 0; j < 4; j++) {
      q[j] = *(const f16x8*)(Bq + bbase + ((size_t)(j * 512 + kc)) * 512);
      k[j] = *(const f16x8*)(Bk + bbase + ((size_t)(j * 512 + kc)) * 512);
    }
  };
  auto compute = [&](const f16* sb, const f16x8* bqf, const f16x8* bkf) {
    f16x8 af[4];
    #pragma unroll
    for (int i = 0; i < 4; i++) {
      const int r = wm * 64 + i * 16 + (lane & 15);
      af[i] = *(const f16x8*)&sb[r * 64 + slotoff];
    }
    #pragma unroll
    for (int i = 0; i < 4; i++)
      #pragma unroll
      for (int j = 0; j < 4; j++) {
        accq[i][j] = __builtin_amdgcn_mfma_f32_16x16x32_f16(af[i], bqf[j], accq[i][j], 0, 0, 0);
        acck[i][j] = __builtin_amdgcn_mfma_f32_16x16x32_f16(af[i], bkf[j], acck[i][j], 0, 0, 0);
      }
  };

  f16x8 bq0[4], bk0[4], bq1[4], bk1[4];
  stageA(0, 0);
  loadB(0, bq0, bk0);
  for (int kk = 0; kk < 16384; kk += 128) {
    __syncthreads();
    stageA(kk + 64, 1);
    loadB(kk + 64, bq1, bk1);
    compute(&smem[0], bq0, bk0);
    __syncthreads();
    if (kk + 128 < 16384) { stageA(kk + 128, 0); loadB(kk + 128, bq0, bk0); }
    compute(&smem[8192], bq1, bk1);
  }

  // ---- k-split reduction + epilogue. C/D: col=lane&15, row=(lane>>4)*4+reg ----
  const int crow = (lane >> 4) * 4;
  const int ccol = lane & 15;
  const int hh = n0 >> 6;
  float* red = (float*)smem + wm * 4096;   // 64x64 f32 per m-half (32 KB total)

  // Q round
  __syncthreads();
  if (ks == 1) {
    #pragma unroll
    for (int i = 0; i < 4; i++)
      #pragma unroll
      for (int j = 0; j < 4; j++)
        #pragma unroll
        for (int r = 0; r < 4; r++)
          red[(i * 16 + crow + r) * 64 + j * 16 + ccol] = accq[i][j][r];
  }
  __syncthreads();
  if (ks == 0) {
    #pragma unroll
    for (int j = 0; j < 4; j++) {
      const int col = n0 + j * 16 + ccol;
      const float bvl = bq[col];
      const int d = j * 16 + ccol;
      #pragma unroll
      for (int i = 0; i < 4; i++)
        #pragma unroll
        for (int r = 0; r < 4; r++) {
          const int row = m0 + wm * 64 + i * 16 + crow + r;
          const int b = row >> 11, t = row & (TSEQ - 1);
          const float v = accq[i][j][r] + red[(i * 16 + crow + r) * 64 + j * 16 + ccol] + bvl;
          oq[((size_t)(b * 16 + hh) * TSEQ + t) * 64 + d] = (f16)v;
        }
    }
  }
  // K round
  __syncthreads();
  if (ks == 1) {
    #pragma unroll
    for (int i = 0; i < 4; i++)
      #pragma unroll
      for (int j = 0; j < 4; j++)
        #pragma unroll
        for (int r = 0; r < 4; r++)
          red[(i * 16 + crow + r) * 64 + j * 16 + ccol] = acck[i][j][r];
  }
  __syncthreads();
  if (ks == 0) {
    #pragma unroll
    for (int j = 0; j < 4; j++) {
      const int col = n0 + j * 16 + ccol;
      const float bvl = bk[col];
      const int d = j * 16 + ccol;
      #pragma unroll
      for (int i = 0; i < 4; i++)
        #pragma unroll
        for (int r = 0; r < 4; r++) {
          const int row = m0 + wm * 64 + i * 16 + crow + r;
          const int b = row >> 11, t = row & (TSEQ - 1);
          const float v = acck[i][j][r] + red[(i * 16 + crow + r) * 64 + j * 16 + ccol] + bvl;
          ok[((size_t)(b * 16 + hh) * TSEQ + t) * 64 + d] = (f16)v;
        }
    }
  }
}

// ---------------- small GEMM (K=1024): v-proj / p-proj ----------------
// MODE 0: fp16 out to (b,h,t,d) layout (v). MODE 1: fp32 out to (b,t,d) d_out (p).
template<int MODE>
__global__ __launch_bounds__(256, 2) void gemm_small(
    const f16* __restrict__ A, const f16* __restrict__ Bw,
    const float* __restrict__ bias, f16* __restrict__ oh, float* __restrict__ ofp)
{
  __shared__ f16 As[128 * 32];
  __shared__ f16 Bs[128 * 32];
  const int tid = threadIdx.x;
  const int lane = tid & 63;
  const int wid = tid >> 6;
  const int m0 = blockIdx.x * 128;
  const int n0 = blockIdx.y * 128;

  const int srow = lane >> 2;
  const int scg = ((lane & 3) ^ ((lane >> 3) & 3)) * 8;
  const int wm = wid & 1;
  const int wn = wid >> 1;

  f32x4 acc[4][4] = {};

  for (int kk = 0; kk < 1024; kk += 32) {
    __syncthreads();
    if (wid < 2) {
      #pragma unroll
      for (int c = 0; c < 4; c++) {
        const int r = wid * 64 + c * 16 + srow;
        const void* g = (const void*)(A + (((size_t)(m0 + r)) << 10) + kk + scg);
        gload_lds16(g, (void*)&As[(wid * 64 + c * 16) * 32]);
      }
    } else {
      #pragma unroll
      for (int c = 0; c < 4; c++) {
        const int r = (wid - 2) * 64 + c * 16 + srow;
        const void* g = (const void*)(Bw + (((size_t)(n0 + r)) << 10) + kk + scg);
        gload_lds16(g, (void*)&Bs[((wid - 2) * 64 + c * 16) * 32]);
      }
    }
    __syncthreads();
    const int koff = ((lane >> 4) ^ ((lane >> 1) & 3)) * 8;
    f16x8 af[4], bf[4];
    #pragma unroll
    for (int i = 0; i < 4; i++) {
      af[i] = *(const f16x8*)&As[(wm * 64 + i * 16 + (lane & 15)) * 32 + koff];
      bf[i] = *(const f16x8*)&Bs[(wn * 64 + i * 16 + (lane & 15)) * 32 + koff];
    }
    #pragma unroll
    for (int i = 0; i < 4; i++)
      #pragma unroll
      for (int j = 0; j < 4; j++)
        acc[i][j] = __builtin_amdgcn_mfma_f32_16x16x32_f16(af[i], bf[j], acc[i][j], 0, 0, 0);
  }

  const int crow = (lane >> 4) * 4;
  const int ccol = lane & 15;
  #pragma unroll
  for (int j = 0; j < 4; j++) {
    const int col = n0 + wn * 64 + j * 16 + ccol;
    const float bvl = bias[col];
    #pragma unroll
    for (int i = 0; i < 4; i++) {
      #pragma unroll
      for (int r = 0; r < 4; r++) {
        const int row = m0 + wm * 64 + i * 16 + crow + r;
        const float val = acc[i][j][r] + bvl;
        if (MODE == 1) {
          ofp[(size_t)row * DDIM + col] = val;
        } else {
          const int b = row >> 11, t = row & (TSEQ - 1);
          const int h = col >> 6, d = col & 63;
          oh[((size_t)(b * 16 + h) * TSEQ + t) * 64 + d] = (f16)val;
        }
      }
    }
  }
}

// ------- log-sparse scores, (b,h,t,d) layout, coalesced + fdot2 -------
// grid 1024 = bh(32) x tc(32); 8 lanes per t-row, shfl-reduce over d.
__global__ __launch_bounds__(256) void score_k(const f16* __restrict__ qh,
                                               const f16* __restrict__ kh,
                                               float* __restrict__ scores) {
  const int bid = blockIdx.x;
  const int bh = bid >> 5, tc = bid & 31;
  const int tid = threadIdx.x;
  const int wave = tid >> 6, lane = tid & 63;
  const int tr = lane >> 3, dc = lane & 7;
  const size_t base = ((size_t)bh) << 17;
  const f16* qb = qh + base;
  const f16* kb = kh + base;

  #pragma unroll
  for (int p = 0; p < 2; p++) {
    const int t = tc * 64 + p * 32 + wave * 8 + tr;
    f16x8 qv = *(const f16x8*)(qb + (size_t)t * 64 + dc * 8);
    const f16x2* qp = (const f16x2*)&qv;
    #pragma unroll
    for (int e = 0; e < 8; e++) {
      const int ts = (t + (1 << e)) & (TSEQ - 1);
      f16x8 kv = *(const f16x8*)(kb + (size_t)ts * 64 + dc * 8);
      const f16x2* kp = (const f16x2*)&kv;
      float s = 0.f;
      #pragma unroll
      for (int j = 0; j < 4; j++) s = __builtin_amdgcn_fdot2(qp[j], kp[j], s, false);
      s += __shfl_xor(s, 1, 64);
      s += __shfl_xor(s, 2, 64);
      s += __shfl_xor(s, 4, 64);
      if (dc == 0) scores[((size_t)(bh * 8 + e) << 11) + t] = s * 0.125f;
    }
  }
}

// ---- in-place softmax over T per (b,h,e) row: 256 rows of 2048 ----
__global__ void softmax_k(float* __restrict__ scores) {
  __shared__ float red[4];
  int row = blockIdx.x;
  float* p = scores + ((size_t)row << 11);
  int tid = threadIdx.x;
  float v[8];
  float4 a = ((const float4*)p)[tid * 2];
  float4 b = ((const float4*)p)[tid * 2 + 1];
  v[0] = a.x; v[1] = a.y; v[2] = a.z; v[3] = a.w;
  v[4] = b.x; v[5] = b.y; v[6] = b.z; v[7] = b.w;
  float m = v[0];
  #pragma unroll
  for (int j = 1; j < 8; j++) m = fmaxf(m, v[j]);
  for (int o = 32; o > 0; o >>= 1) m = fmaxf(m, __shfl_xor(m, o, 64));
  if ((tid & 63) == 0) red[tid >> 6] = m;
  __syncthreads();
  m = fmaxf(fmaxf(red[0], red[1]), fmaxf(red[2], red[3]));
  __syncthreads();
  float s = 0.f;
  #pragma unroll
  for (int j = 0; j < 8; j++) { v[j] = __expf(v[j] - m); s += v[j]; }
  for (int o = 32; o > 0; o >>= 1) s += __shfl_xor(s, o, 64);
  if ((tid & 63) == 0) red[tid >> 6] = s;
  __syncthreads();
  s = (red[0] + red[1]) + (red[2] + red[3]);
  float inv = 1.0f / s;
  float4 o1 = make_float4(v[0] * inv, v[1] * inv, v[2] * inv, v[3] * inv);
  float4 o2 = make_float4(v[4] * inv, v[5] * inv, v[6] * inv, v[7] * inv);
  ((float4*)p)[tid * 2] = o1;
  ((float4*)p)[tid * 2 + 1] = o2;
}

// ------- local windowed attention + log-sparse combine -> outh (b,t,d) -------
__global__ __launch_bounds__(256) void attn_out_k(
    const f16* __restrict__ qh, const f16* __restrict__ kh, const f16* __restrict__ vh,
    const float* __restrict__ alpha, f16* __restrict__ outh)
{
  __shared__ f16 qL[64 * 64];
  __shared__ f16 kL[80 * 64];
  __shared__ f16 vL[208 * 64];
  __shared__ float scL[64 * 16];
  __shared__ float aL[8 * 64];
  const int bh = blockIdx.x, tc = blockIdx.y;
  const int t0 = tc * 64;
  const int tid = threadIdx.x;
  const size_t base = ((size_t)bh) << 17;

  for (int idx = tid; idx < 64 * 8; idx += 256) {
    int r = idx >> 3, c = idx & 7, sl = c ^ (r & 7);
    *(uint4*)&qL[r * 64 + sl * 8] = *(const uint4*)(qh + base + (size_t)(t0 + r) * 64 + c * 8);
  }
  for (int idx = tid; idx < 79 * 8; idx += 256) {
    int r = idx >> 3, c = idx & 7, sl = c ^ (r & 7);
    int g = t0 - 15 + r;
    uint4 val = (g < 0) ? make_uint4(0, 0, 0, 0)
                        : *(const uint4*)(kh + base + (size_t)g * 64 + c * 8);
    *(uint4*)&kL[r * 64 + sl * 8] = val;
  }
  for (int idx = tid; idx < 207 * 8; idx += 256) {
    int r = idx >> 3, c = idx & 7, sl = c ^ (r & 7);
    int g = t0 - 15 + r;
    uint4 val;
    if (g < 0) val = make_uint4(0, 0, 0, 0);
    else {
      if (g >= TSEQ) g -= TSEQ;
      val = *(const uint4*)(vh + base + (size_t)g * 64 + c * 8);
    }
    *(uint4*)&vL[r * 64 + sl * 8] = val;
  }
  for (int idx = tid; idx < 512; idx += 256) {
    int e = idx >> 6, i = idx & 63;
    aL[e * 64 + i] = alpha[((size_t)(bh * 8 + e) << 11) + t0 + i];
  }
  __syncthreads();

  {
    const int tl = tid & 63;
    const int wg = tid >> 6;
    f16x8 qv[8];
    #pragma unroll
    for (int c = 0; c < 8; c++) qv[c] = *(const f16x8*)&qL[tl * 64 + ((c ^ (tl & 7)) * 8)];
    const f16x2* qp = (const f16x2*)&qv[0];
    #pragma unroll
    for (int wi = 0; wi < 4; wi++) {
      const int w = wg * 4 + wi;
      const int r = tl + w;
      float s = 0.f;
      #pragma unroll
      for (int c = 0; c < 8; c++) {
        f16x8 kv = *(const f16x8*)&kL[r * 64 + ((c ^ (r & 7)) * 8)];
        const f16x2* kp = (const f16x2*)&kv;
        #pragma unroll
        for (int j = 0; j < 4; j++) s = __builtin_amdgcn_fdot2(qp[c * 4 + j], kp[j], s, false);
      }
      scL[tl * 16 + w] = s * 0.125f;
    }
  }
  __syncthreads();

  if (tid < 64) {
    float sc[16];
    float m = -1e30f;
    #pragma unroll
    for (int w = 0; w < 16; w++) { sc[w] = scL[tid * 16 + w]; m = fmaxf(m, sc[w]); }
    float sum = 0.f;
    #pragma unroll
    for (int w = 0; w < 16; w++) { sc[w] = __expf(sc[w] - m); sum += sc[w]; }
    float inv = 1.0f / sum;
    #pragma unroll
    for (int w = 0; w < 16; w++) scL[tid * 16 + w] = sc[w] * inv;
  }
  __syncthreads();

  {
    const int tl = tid >> 2;
    const int qd = tid & 3;
    float accv[16] = {};
    #pragma unroll
    for (int w = 0; w < 16; w++) {
      const float pw_ = scL[tl * 16 + w];
      const int r = tl + w;
      #pragma unroll
      for (int c2 = 0; c2 < 2; c2++) {
        const int c = qd * 2 + c2;
        f16x8 v = *(const f16x8*)&vL[r * 64 + ((c ^ (r & 7)) * 8)];
        #pragma unroll
        for (int j = 0; j < 8; j++) accv[c2 * 8 + j] += pw_ * (float)v[j];
      }
    }
    #pragma unroll
    for (int e = 0; e < 8; e++) {
      const float a = aL[e * 64 + tl];
      const int r = tl + 15 + (1 << e);
      #pragma unroll
      for (int c2 = 0; c2 < 2; c2++) {
        const int c = qd * 2 + c2;
        f16x8 v = *(const f16x8*)&vL[r * 64 + ((c ^ (r & 7)) * 8)];
        #pragma unroll
        for (int j = 0; j < 8; j++) accv[c2 * 8 + j] += a * (float)v[j];
      }
    }
    const int b = bh >> 4, h = bh & 15;
    f16* orow = outh + ((size_t)(b * TSEQ + t0 + tl)) * DDIM + h * 64 + qd * 16;
    #pragma unroll
    for (int c2 = 0; c2 < 2; c2++) {
      f16x8 v;
      #pragma unroll
      for (int j = 0; j < 8; j++) v[j] = (f16)accv[c2 * 8 + j];
      *(f16x8*)(orow + c2 * 8) = v;
    }
  }
}

extern "C" void kernel_launch(void* const* d_in, const int* in_sizes, int n_in,
                              void* d_out, int out_size, void* d_ws, size_t ws_size,
                              hipStream_t stream) {
  (void)in_sizes; (void)n_in; (void)out_size; (void)ws_size;
  const float* x   = (const float*)d_in[0];
  const float* q_w = (const float*)d_in[1];
  const float* q_b = (const float*)d_in[2];
  const float* k_w = (const float*)d_in[3];
  const float* k_b = (const float*)d_in[4];
  const float* v_w = (const float*)d_in[5];
  const float* v_b = (const float*)d_in[6];
  const float* p_w = (const float*)d_in[7];
  const float* p_b = (const float*)d_in[8];
  float* out = (float*)d_out;

  char* ws = (char*)d_ws;
  f16* xh      = (f16*)(ws);                 //  8.4 MB (b,t,d)
  f16* qwh     = (f16*)(ws + 8388608);       // 33.6 MB frag-major
  f16* kwh     = (f16*)(ws + 41943040);      // 33.6 MB frag-major
  f16* vwh     = (f16*)(ws + 75497472);      //  2.1 MB flat [o][k]
  f16* pwh     = (f16*)(ws + 77594624);      //  2.1 MB flat [o][k]
  f16* qh      = (f16*)(ws + 79691776);      //  8.4 MB (b,h,t,d)
  f16* kh      = (f16*)(ws + 88080384);      //  8.4 MB (b,h,t,d)
  f16* vh      = (f16*)(ws + 96468992);      //  8.4 MB (b,h,t,d)
  f16* outh    = (f16*)(ws + 104857600);     //  8.4 MB (b,t,d)
  float* alpha = (float*)(ws + 113246208);   //  2.1 MB (B*H*E, T)
  // total 115.4 MB

  cvt_all<<<6144, 256, 0, stream>>>(x, v_w, p_w, xh, vwh, pwh);
  cvt_w_frag<<<2048, 256, 0, stream>>>(q_w, k_w, qwh, kwh);

  // fused q+k conv-GEMM (A LDS-staged, B direct-from-global), 512 blocks = 2/CU
  gemm_qk<<<dim3(32, 16), 256, 0, stream>>>(xh, qwh, kwh, q_b, k_b, qh, kh);
  // v projection
  gemm_small<0><<<dim3(32, 8), 256, 0, stream>>>(xh, vwh, v_b, vh, nullptr);

  score_k<<<1024, 256, 0, stream>>>(qh, kh, alpha);
  softmax_k<<<256, 256, 0, stream>>>(alpha);
  attn_out_k<<<dim3(32, 32), 256, 0, stream>>>(qh, kh, vh, alpha, outh);

  // final projection -> fp32 d_out
  gemm_small<1><<<dim3(32, 8), 256, 0, stream>>>(outh, pwh, p_b, nullptr, out);
}

// Round 8
// 538.494 us; speedup vs baseline: 1.0197x; 1.0197x over previous
//
#include <hip/hip_runtime.h>
#include <cstdint>
#include <cstddef>

#define TSEQ 2048
#define DDIM 1024

typedef _Float16 f16;
typedef _Float16 f16x2 __attribute__((ext_vector_type(2)));
typedef _Float16 f16x4 __attribute__((ext_vector_type(4)));
typedef _Float16 f16x8 __attribute__((ext_vector_type(8)));
typedef float f32x4 __attribute__((ext_vector_type(4)));

// q,k,v live in (b,h,t,d) layout: ((b*16+h)*2048 + t)*64 + d.
// Conv weights: wh[o][w*1024 + i] (K-contiguous for the GEMM B side).

__device__ __align__(16) static const unsigned char g_zero16[16] = {};

__device__ __forceinline__ void gload_lds16(const void* g, void* l) {
  __builtin_amdgcn_global_load_lds(
      (const __attribute__((address_space(1))) void*)g,
      (__attribute__((address_space(3))) void*)l, 16, 0, 0);
}

// ------------- fused fp32->fp16 converts (x, v_w, p_w) -------------
__global__ void cvt_all(const float* __restrict__ x, const float* __restrict__ vw,
                        const float* __restrict__ pw,
                        f16* __restrict__ xh, f16* __restrict__ vwh, f16* __restrict__ pwh) {
  int b = blockIdx.x;
  const float* src; f16* dst; int i;
  if (b < 4096)      { src = x;  dst = xh;  i = b * 256 + threadIdx.x; }
  else if (b < 5120) { src = vw; dst = vwh; i = (b - 4096) * 256 + threadIdx.x; }
  else               { src = pw; dst = pwh; i = (b - 5120) * 256 + threadIdx.x; }
  float4 v = ((const float4*)src)[i];
  f16x4 h = { (f16)v.x, (f16)v.y, (f16)v.z, (f16)v.w };
  ((f16x4*)dst)[i] = h;
}

// ------- conv weights w[o][i][W] -> wh[o][w*1024+i], vectorized both sides -------
// One o-row per block (2048 blocks: q then k). float4 reads, f16x8 writes.
// Phase 1 must cover 4096 float4 slots (1024 i x 4 w-quads) -> 16 iterations.
__global__ __launch_bounds__(256) void cvt_w_tr(const float* __restrict__ qw,
                                                const float* __restrict__ kw,
                                                f16* __restrict__ qd, f16* __restrict__ kd) {
  __shared__ f16 tile[16][1032];   // [w][i], +16B pad per row
  const int o = blockIdx.x;
  const float* src; f16* dst;
  if (o < 1024) { src = qw + (size_t)o * 16384; dst = qd + (size_t)o * 16384; }
  else          { src = kw + (size_t)(o - 1024) * 16384; dst = kd + (size_t)(o - 1024) * 16384; }
  const int tid = threadIdx.x;
  #pragma unroll
  for (int p = 0; p < 16; p++) {
    const int idx = p * 256 + tid;          // 0..4095
    const int i = idx >> 2, wq = idx & 3;   // i-channel 0..1023, w-quad 0..3
    float4 v = *(const float4*)(src + (size_t)i * 16 + wq * 4);
    tile[wq * 4 + 0][i] = (f16)v.x;
    tile[wq * 4 + 1][i] = (f16)v.y;
    tile[wq * 4 + 2][i] = (f16)v.z;
    tile[wq * 4 + 3][i] = (f16)v.w;
  }
  __syncthreads();
  #pragma unroll
  for (int p = 0; p < 8; p++) {
    const int c = p * 256 + tid;            // 0..2047
    const int w = c >> 7, i8 = (c & 127) * 8;
    *(f16x8*)(dst + (size_t)w * 1024 + i8) = *(const f16x8*)&tile[w][i8];
  }
}

// ------------- fused q+k conv-GEMM, k-split, BK=64, double-buffered -------------
// (round-5 body, known 279 us / 985 TF)
__global__ __launch_bounds__(256, 2) void gemm_qk(
    const f16* __restrict__ xh,
    const f16* __restrict__ Bq, const f16* __restrict__ Bk,
    const float* __restrict__ bq, const float* __restrict__ bk,
    f16* __restrict__ oq, f16* __restrict__ ok)
{
  __shared__ __align__(16) f16 smem[32768];   // 2 stages x (As 8192 | Bq 4096 | Bk 4096)
  const int tid = threadIdx.x;
  const int lane = tid & 63;
  const int wid = tid >> 6;
  const int wm = wid & 1;
  const int ks = wid >> 1;

  const int m0 = blockIdx.x * 128;
  const int n0 = blockIdx.y * 64;
  const int bT = m0 & ~(TSEQ - 1);
  const int t0 = m0 & (TSEQ - 1);

  const int srow = lane >> 3;                           // staging row within inst
  const int scg = ((lane & 7) ^ ((lane >> 3) & 7)) * 8; // swizzled chunk (f16 units)

  f32x4 accq[4][4] = {};
  f32x4 acck[4][4] = {};

  // read-side slot: chunk cg = ks*4 + (lane>>4), slot = cg ^ (lane&7)
  const int slotoff = (((ks * 4 + (lane >> 4)) ^ (lane & 7)) * 8);

  auto stage = [&](int kk, int buf) {
    f16* sb = &smem[buf * 16384];
    if (wid < 2) {
      const int w = kk >> 10;
      const int i0 = (kk & (DDIM - 1)) + scg;
      #pragma unroll
      for (int c = 0; c < 8; c++) {
        const int s = wid * 8 + c;
        const int r = s * 8 + srow;
        const int srcT = t0 + r + w - 15;
        const void* g = (srcT >= 0)
            ? (const void*)(xh + (((size_t)(bT + srcT)) << 10) + i0)
            : (const void*)g_zero16;
        gload_lds16(g, (void*)&sb[s * 512]);
      }
    } else if (wid == 2) {
      #pragma unroll
      for (int c = 0; c < 8; c++) {
        const int r = c * 8 + srow;
        const void* g = (const void*)(Bq + ((size_t)(n0 + r) << 14) + kk + scg);
        gload_lds16(g, (void*)&sb[8192 + c * 512]);
      }
    } else {
      #pragma unroll
      for (int c = 0; c < 8; c++) {
        const int r = c * 8 + srow;
        const void* g = (const void*)(Bk + ((size_t)(n0 + r) << 14) + kk + scg);
        gload_lds16(g, (void*)&sb[12288 + c * 512]);
      }
    }
  };

  stage(0, 0);
  for (int kk = 0; kk < 16384; kk += 64) {
    const int buf = (kk >> 6) & 1;
    __syncthreads();
    if (kk + 64 < 16384) stage(kk + 64, buf ^ 1);

    const f16* sb = &smem[buf * 16384];
    f16x8 af[4], bfq[4], bfk[4];
    #pragma unroll
    for (int i = 0; i < 4; i++) {
      const int r = wm * 64 + i * 16 + (lane & 15);
      af[i] = *(const f16x8*)&sb[r * 64 + slotoff];
    }
    #pragma unroll
    for (int j = 0; j < 4; j++) {
      const int r = j * 16 + (lane & 15);
      bfq[j] = *(const f16x8*)&sb[8192 + r * 64 + slotoff];
      bfk[j] = *(const f16x8*)&sb[12288 + r * 64 + slotoff];
    }
    #pragma unroll
    for (int i = 0; i < 4; i++)
      #pragma unroll
      for (int j = 0; j < 4; j++) {
        accq[i][j] = __builtin_amdgcn_mfma_f32_16x16x32_f16(af[i], bfq[j], accq[i][j], 0, 0, 0);
        acck[i][j] = __builtin_amdgcn_mfma_f32_16x16x32_f16(af[i], bfk[j], acck[i][j], 0, 0, 0);
      }
  }

  // ---- k-split reduction + epilogue. C/D: col=lane&15, row=(lane>>4)*4+reg ----
  const int crow = (lane >> 4) * 4;
  const int ccol = lane & 15;
  const int hh = n0 >> 6;
  float* red = (float*)smem + wm * 4096;   // 64x64 f32 per m-half

  // Q round
  __syncthreads();
  if (ks == 1) {
    #pragma unroll
    for (int i = 0; i < 4; i++)
      #pragma unroll
      for (int j = 0; j < 4; j++)
        #pragma unroll
        for (int r = 0; r < 4; r++)
          red[(i * 16 + crow + r) * 64 + j * 16 + ccol] = accq[i][j][r];
  }
  __syncthreads();
  if (ks == 0) {
    #pragma unroll
    for (int j = 0; j < 4; j++) {
      const int col = n0 + j * 16 + ccol;
      const float bvl = bq[col];
      const int d = j * 16 + ccol;
      #pragma unroll
      for (int i = 0; i < 4; i++)
        #pragma unroll
        for (int r = 0; r < 4; r++) {
          const int row = m0 + wm * 64 + i * 16 + crow + r;
          const int b = row >> 11, t = row & (TSEQ - 1);
          const float v = accq[i][j][r] + red[(i * 16 + crow + r) * 64 + j * 16 + ccol] + bvl;
          oq[((size_t)(b * 16 + hh) * TSEQ + t) * 64 + d] = (f16)v;
        }
    }
  }
  // K round
  __syncthreads();
  if (ks == 1) {
    #pragma unroll
    for (int i = 0; i < 4; i++)
      #pragma unroll
      for (int j = 0; j < 4; j++)
        #pragma unroll
        for (int r = 0; r < 4; r++)
          red[(i * 16 + crow + r) * 64 + j * 16 + ccol] = acck[i][j][r];
  }
  __syncthreads();
  if (ks == 0) {
    #pragma unroll
    for (int j = 0; j < 4; j++) {
      const int col = n0 + j * 16 + ccol;
      const float bvl = bk[col];
      const int d = j * 16 + ccol;
      #pragma unroll
      for (int i = 0; i < 4; i++)
        #pragma unroll
        for (int r = 0; r < 4; r++) {
          const int row = m0 + wm * 64 + i * 16 + crow + r;
          const int b = row >> 11, t = row & (TSEQ - 1);
          const float v = acck[i][j][r] + red[(i * 16 + crow + r) * 64 + j * 16 + ccol] + bvl;
          ok[((size_t)(b * 16 + hh) * TSEQ + t) * 64 + d] = (f16)v;
        }
    }
  }
}

// ---------------- small GEMM (K=1024): v-proj / p-proj ----------------
// MODE 0: fp16 out to (b,h,t,d) layout (v). MODE 1: fp32 out to (b,t,d) d_out (p).
template<int MODE>
__global__ __launch_bounds__(256, 2) void gemm_small(
    const f16* __restrict__ A, const f16* __restrict__ Bw,
    const float* __restrict__ bias, f16* __restrict__ oh, float* __restrict__ ofp)
{
  __shared__ f16 As[128 * 32];
  __shared__ f16 Bs[128 * 32];
  const int tid = threadIdx.x;
  const int lane = tid & 63;
  const int wid = tid >> 6;
  const int m0 = blockIdx.x * 128;
  const int n0 = blockIdx.y * 128;

  const int srow = lane >> 2;
  const int scg = ((lane & 3) ^ ((lane >> 3) & 3)) * 8;
  const int wm = wid & 1;
  const int wn = wid >> 1;

  f32x4 acc[4][4] = {};

  for (int kk = 0; kk < 1024; kk += 32) {
    __syncthreads();
    if (wid < 2) {
      #pragma unroll
      for (int c = 0; c < 4; c++) {
        const int r = wid * 64 + c * 16 + srow;
        const void* g = (const void*)(A + (((size_t)(m0 + r)) << 10) + kk + scg);
        gload_lds16(g, (void*)&As[(wid * 64 + c * 16) * 32]);
      }
    } else {
      #pragma unroll
      for (int c = 0; c < 4; c++) {
        const int r = (wid - 2) * 64 + c * 16 + srow;
        const void* g = (const void*)(Bw + (((size_t)(n0 + r)) << 10) + kk + scg);
        gload_lds16(g, (void*)&Bs[((wid - 2) * 64 + c * 16) * 32]);
      }
    }
    __syncthreads();
    const int koff = ((lane >> 4) ^ ((lane >> 1) & 3)) * 8;
    f16x8 af[4], bf[4];
    #pragma unroll
    for (int i = 0; i < 4; i++) {
      af[i] = *(const f16x8*)&As[(wm * 64 + i * 16 + (lane & 15)) * 32 + koff];
      bf[i] = *(const f16x8*)&Bs[(wn * 64 + i * 16 + (lane & 15)) * 32 + koff];
    }
    #pragma unroll
    for (int i = 0; i < 4; i++)
      #pragma unroll
      for (int j = 0; j < 4; j++)
        acc[i][j] = __builtin_amdgcn_mfma_f32_16x16x32_f16(af[i], bf[j], acc[i][j], 0, 0, 0);
  }

  const int crow = (lane >> 4) * 4;
  const int ccol = lane & 15;
  #pragma unroll
  for (int j = 0; j < 4; j++) {
    const int col = n0 + wn * 64 + j * 16 + ccol;
    const float bvl = bias[col];
    #pragma unroll
    for (int i = 0; i < 4; i++) {
      #pragma unroll
      for (int r = 0; r < 4; r++) {
        const int row = m0 + wm * 64 + i * 16 + crow + r;
        const float val = acc[i][j][r] + bvl;
        if (MODE == 1) {
          ofp[(size_t)row * DDIM + col] = val;
        } else {
          const int b = row >> 11, t = row & (TSEQ - 1);
          const int h = col >> 6, d = col & 63;
          oh[((size_t)(b * 16 + h) * TSEQ + t) * 64 + d] = (f16)val;
        }
      }
    }
  }
}

// ------- log-sparse scores, (b,h,t,d) layout, coalesced + fdot2 -------
// grid 1024 = bh(32) x tc(32); 8 lanes per t-row, shfl-reduce over d.
__global__ __launch_bounds__(256) void score_k(const f16* __restrict__ qh,
                                               const f16* __restrict__ kh,
                                               float* __restrict__ scores) {
  const int bid = blockIdx.x;
  const int bh = bid >> 5, tc = bid & 31;
  const int tid = threadIdx.x;
  const int wave = tid >> 6, lane = tid & 63;
  const int tr = lane >> 3, dc = lane & 7;
  const size_t base = ((size_t)bh) << 17;
  const f16* qb = qh + base;
  const f16* kb = kh + base;

  #pragma unroll
  for (int p = 0; p < 2; p++) {
    const int t = tc * 64 + p * 32 + wave * 8 + tr;
    f16x8 qv = *(const f16x8*)(qb + (size_t)t * 64 + dc * 8);
    const f16x2* qp = (const f16x2*)&qv;
    #pragma unroll
    for (int e = 0; e < 8; e++) {
      const int ts = (t + (1 << e)) & (TSEQ - 1);
      f16x8 kv = *(const f16x8*)(kb + (size_t)ts * 64 + dc * 8);
      const f16x2* kp = (const f16x2*)&kv;
      float s = 0.f;
      #pragma unroll
      for (int j = 0; j < 4; j++) s = __builtin_amdgcn_fdot2(qp[j], kp[j], s, false);
      s += __shfl_xor(s, 1, 64);
      s += __shfl_xor(s, 2, 64);
      s += __shfl_xor(s, 4, 64);
      if (dc == 0) scores[((size_t)(bh * 8 + e) << 11) + t] = s * 0.125f;
    }
  }
}

// ---- in-place softmax over T per (b,h,e) row: 256 rows of 2048 ----
__global__ void softmax_k(float* __restrict__ scores) {
  __shared__ float red[4];
  int row = blockIdx.x;
  float* p = scores + ((size_t)row << 11);
  int tid = threadIdx.x;
  float v[8];
  float4 a = ((const float4*)p)[tid * 2];
  float4 b = ((const float4*)p)[tid * 2 + 1];
  v[0] = a.x; v[1] = a.y; v[2] = a.z; v[3] = a.w;
  v[4] = b.x; v[5] = b.y; v[6] = b.z; v[7] = b.w;
  float m = v[0];
  #pragma unroll
  for (int j = 1; j < 8; j++) m = fmaxf(m, v[j]);
  for (int o = 32; o > 0; o >>= 1) m = fmaxf(m, __shfl_xor(m, o, 64));
  if ((tid & 63) == 0) red[tid >> 6] = m;
  __syncthreads();
  m = fmaxf(fmaxf(red[0], red[1]), fmaxf(red[2], red[3]));
  __syncthreads();
  float s = 0.f;
  #pragma unroll
  for (int j = 0; j < 8; j++) { v[j] = __expf(v[j] - m); s += v[j]; }
  for (int o = 32; o > 0; o >>= 1) s += __shfl_xor(s, o, 64);
  if ((tid & 63) == 0) red[tid >> 6] = s;
  __syncthreads();
  s = (red[0] + red[1]) + (red[2] + red[3]);
  float inv = 1.0f / s;
  float4 o1 = make_float4(v[0] * inv, v[1] * inv, v[2] * inv, v[3] * inv);
  float4 o2 = make_float4(v[4] * inv, v[5] * inv, v[6] * inv, v[7] * inv);
  ((float4*)p)[tid * 2] = o1;
  ((float4*)p)[tid * 2 + 1] = o2;
}

// ------- local windowed attention + log-sparse combine -> outh (b,t,d) -------
__global__ __launch_bounds__(256) void attn_out_k(
    const f16* __restrict__ qh, const f16* __restrict__ kh, const f16* __restrict__ vh,
    const float* __restrict__ alpha, f16* __restrict__ outh)
{
  __shared__ f16 qL[64 * 64];
  __shared__ f16 kL[80 * 64];
  __shared__ f16 vL[208 * 64];
  __shared__ float scL[64 * 16];
  __shared__ float aL[8 * 64];
  const int bh = blockIdx.x, tc = blockIdx.y;
  const int t0 = tc * 64;
  const int tid = threadIdx.x;
  const size_t base = ((size_t)bh) << 17;

  for (int idx = tid; idx < 64 * 8; idx += 256) {
    int r = idx >> 3, c = idx & 7, sl = c ^ (r & 7);
    *(uint4*)&qL[r * 64 + sl * 8] = *(const uint4*)(qh + base + (size_t)(t0 + r) * 64 + c * 8);
  }
  for (int idx = tid; idx < 79 * 8; idx += 256) {
    int r = idx >> 3, c = idx & 7, sl = c ^ (r & 7);
    int g = t0 - 15 + r;
    uint4 val = (g < 0) ? make_uint4(0, 0, 0, 0)
                        : *(const uint4*)(kh + base + (size_t)g * 64 + c * 8);
    *(uint4*)&kL[r * 64 + sl * 8] = val;
  }
  for (int idx = tid; idx < 207 * 8; idx += 256) {
    int r = idx >> 3, c = idx & 7, sl = c ^ (r & 7);
    int g = t0 - 15 + r;
    uint4 val;
    if (g < 0) val = make_uint4(0, 0, 0, 0);
    else {
      if (g >= TSEQ) g -= TSEQ;
      val = *(const uint4*)(vh + base + (size_t)g * 64 + c * 8);
    }
    *(uint4*)&vL[r * 64 + sl * 8] = val;
  }
  for (int idx = tid; idx < 512; idx += 256) {
    int e = idx >> 6, i = idx & 63;
    aL[e * 64 + i] = alpha[((size_t)(bh * 8 + e) << 11) + t0 + i];
  }
  __syncthreads();

  {
    const int tl = tid & 63;
    const int wg = tid >> 6;
    f16x8 qv[8];
    #pragma unroll
    for (int c = 0; c < 8; c++) qv[c] = *(const f16x8*)&qL[tl * 64 + ((c ^ (tl & 7)) * 8)];
    const f16x2* qp = (const f16x2*)&qv[0];
    #pragma unroll
    for (int wi = 0; wi < 4; wi++) {
      const int w = wg * 4 + wi;
      const int r = tl + w;
      float s = 0.f;
      #pragma unroll
      for (int c = 0; c < 8; c++) {
        f16x8 kv = *(const f16x8*)&kL[r * 64 + ((c ^ (r & 7)) * 8)];
        const f16x2* kp = (const f16x2*)&kv;
        #pragma unroll
        for (int j = 0; j < 4; j++) s = __builtin_amdgcn_fdot2(qp[c * 4 + j], kp[j], s, false);
      }
      scL[tl * 16 + w] = s * 0.125f;
    }
  }
  __syncthreads();

  if (tid < 64) {
    float sc[16];
    float m = -1e30f;
    #pragma unroll
    for (int w = 0; w < 16; w++) { sc[w] = scL[tid * 16 + w]; m = fmaxf(m, sc[w]); }
    float sum = 0.f;
    #pragma unroll
    for (int w = 0; w < 16; w++) { sc[w] = __expf(sc[w] - m); sum += sc[w]; }
    float inv = 1.0f / sum;
    #pragma unroll
    for (int w = 0; w < 16; w++) scL[tid * 16 + w] = sc[w] * inv;
  }
  __syncthreads();

  {
    const int tl = tid >> 2;
    const int qd = tid & 3;
    float accv[16] = {};
    #pragma unroll
    for (int w = 0; w < 16; w++) {
      const float pw_ = scL[tl * 16 + w];
      const int r = tl + w;
      #pragma unroll
      for (int c2 = 0; c2 < 2; c2++) {
        const int c = qd * 2 + c2;
        f16x8 v = *(const f16x8*)&vL[r * 64 + ((c ^ (r & 7)) * 8)];
        #pragma unroll
        for (int j = 0; j < 8; j++) accv[c2 * 8 + j] += pw_ * (float)v[j];
      }
    }
    #pragma unroll
    for (int e = 0; e < 8; e++) {
      const float a = aL[e * 64 + tl];
      const int r = tl + 15 + (1 << e);
      #pragma unroll
      for (int c2 = 0; c2 < 2; c2++) {
        const int c = qd * 2 + c2;
        f16x8 v = *(const f16x8*)&vL[r * 64 + ((c ^ (r & 7)) * 8)];
        #pragma unroll
        for (int j = 0; j < 8; j++) accv[c2 * 8 + j] += a * (float)v[j];
      }
    }
    const int b = bh >> 4, h = bh & 15;
    f16* orow = outh + ((size_t)(b * TSEQ + t0 + tl)) * DDIM + h * 64 + qd * 16;
    #pragma unroll
    for (int c2 = 0; c2 < 2; c2++) {
      f16x8 v;
      #pragma unroll
      for (int j = 0; j < 8; j++) v[j] = (f16)accv[c2 * 8 + j];
      *(f16x8*)(orow + c2 * 8) = v;
    }
  }
}

extern "C" void kernel_launch(void* const* d_in, const int* in_sizes, int n_in,
                              void* d_out, int out_size, void* d_ws, size_t ws_size,
                              hipStream_t stream) {
  (void)in_sizes; (void)n_in; (void)out_size; (void)ws_size;
  const float* x   = (const float*)d_in[0];
  const float* q_w = (const float*)d_in[1];
  const float* q_b = (const float*)d_in[2];
  const float* k_w = (const float*)d_in[3];
  const float* k_b = (const float*)d_in[4];
  const float* v_w = (const float*)d_in[5];
  const float* v_b = (const float*)d_in[6];
  const float* p_w = (const float*)d_in[7];
  const float* p_b = (const float*)d_in[8];
  float* out = (float*)d_out;

  char* ws = (char*)d_ws;
  f16* xh      = (f16*)(ws);                 //  8.4 MB (b,t,d)
  f16* qwh     = (f16*)(ws + 8388608);       // 33.6 MB [o][w*1024+i]
  f16* kwh     = (f16*)(ws + 41943040);      // 33.6 MB [o][w*1024+i]
  f16* vwh     = (f16*)(ws + 75497472);      //  2.1 MB flat [o][k]
  f16* pwh     = (f16*)(ws + 77594624);      //  2.1 MB flat [o][k]
  f16* qh      = (f16*)(ws + 79691776);      //  8.4 MB (b,h,t,d)
  f16* kh      = (f16*)(ws + 88080384);      //  8.4 MB (b,h,t,d)
  f16* vh      = (f16*)(ws + 96468992);      //  8.4 MB (b,h,t,d)
  f16* outh    = (f16*)(ws + 104857600);     //  8.4 MB (b,t,d)
  float* alpha = (float*)(ws + 113246208);   //  2.1 MB (B*H*E, T)
  // total 115.4 MB

  cvt_all<<<6144, 256, 0, stream>>>(x, v_w, p_w, xh, vwh, pwh);
  cvt_w_tr<<<2048, 256, 0, stream>>>(q_w, k_w, qwh, kwh);

  // fused q+k conv-GEMM (A shared, LDS double-buffered), 512 blocks = 2/CU
  gemm_qk<<<dim3(32, 16), 256, 0, stream>>>(xh, qwh, kwh, q_b, k_b, qh, kh);
  // v projection
  gemm_small<0><<<dim3(32, 8), 256, 0, stream>>>(xh, vwh, v_b, vh, nullptr);

  score_k<<<1024, 256, 0, stream>>>(qh, kh, alpha);
  softmax_k<<<256, 256, 0, stream>>>(alpha);
  attn_out_k<<<dim3(32, 32), 256, 0, stream>>>(qh, kh, vh, alpha, outh);

  // final projection -> fp32 d_out
  gemm_small<1><<<dim3(32, 8), 256, 0, stream>>>(outh, pwh, p_b, nullptr, out);
}